// Round 2
// baseline (152.907 us; speedup 1.0000x reference)
//
#include <hip/hip_runtime.h>
#include <math.h>

#define H 128
#define MUL 32
#define NC (5 * MUL * MUL)   // 5120 columns of R
#define DD (4 * MUL)         // 128 output dim
#define NIV (H + 1)          // max intervals = 129
#define NMAX 4000

// Static device scratch (no hipMalloc, no d_ws dependency). Recomputed every launch.
__device__ float g_bp[H];            // sorted breakpoints (invalid = +huge)
__device__ int   g_nbp;              // number of valid breakpoints
__device__ float g_rmid[NIV];        // representative radius per interval
__device__ float g_A[NIV * NC];      // R = rad*A + B per interval
__device__ float g_B[NIV * NC];
__device__ float4 g_ey[NMAX];        // (Y0,Y1,Y2, radius)
__device__ int    g_eidx[NMAX];      // interval index, -1 => fallback (kernel2)

__device__ __forceinline__ float sel3(int i, float a, float b, float c) {
    return (i == 0) ? a : ((i == 1) ? b : c);
}

// ---------------- P1: breakpoints, sort, interval midpoints ----------------
__global__ void prep_bp(const float* __restrict__ W1, const float* __restrict__ b1) {
    __shared__ float bp[H];
    __shared__ float sorted[H];
    int k = threadIdx.x;             // blockDim = 128
    float a = W1[k], b = b1[k];
    float v = 3.0e38f;               // invalid sentinel
    if (a != 0.0f) {
        float t = -b / a;
        if (t > 0.0f) v = t;         // only breakpoints in (0, inf) matter (radius >= 0)
    }
    bp[k] = v;
    __syncthreads();
    int rank = 0, nv = 0;
    #pragma unroll 8
    for (int j = 0; j < H; ++j) {
        float bj = bp[j];
        rank += (bj < v) || (bj == v && j < k);
        nv   += (bj < 3.0e38f);
    }
    sorted[rank] = v;
    __syncthreads();
    g_bp[k] = sorted[k];
    if (k == 0) g_nbp = nv;
    int nbp = nv;
    for (int i = k; i <= H; i += H) {   // i = k, and i = 128 for k==0
        float rm;
        if (nbp == 0)       rm = 1.0f;
        else if (i == 0)    rm = 0.5f * sorted[0];
        else if (i >= nbp)  rm = sorted[nbp - 1] + 1.0f;
        else                rm = 0.5f * (sorted[i - 1] + sorted[i]);
        g_rmid[i] = rm;
    }
}

// ---------------- P1b: per-edge radius / Y1 / mask / interval index ----------------
__global__ void prep_edges(const float* __restrict__ r, int N) {
    int n = blockIdx.x * blockDim.x + threadIdx.x;
    if (n >= N) return;
    float x = r[3 * n], y = r[3 * n + 1], z = r[3 * n + 2];
    float rad = sqrtf(x * x + y * y + z * z);
    bool mask = rad > 0.1f;
    float inv = mask ? (1.7320508075688772f / rad) : 0.0f;   // sqrt(3)/rad
    g_ey[n] = make_float4(x * inv, y * inv, z * inv, rad);
    int idx = -1;
    if (mask) {
        int nbp = g_nbp;
        idx = 0;
        for (int j = 0; j < nbp; ++j) idx += (g_bp[j] < rad) ? 1 : 0;
    }
    g_eidx[n] = idx;
}

// ---------------- P2: per-interval rank-1 tables A,B ----------------
__global__ __launch_bounds__(256) void prep_tab(const float* __restrict__ W1,
                                                const float* __restrict__ b1,
                                                const float* __restrict__ W2,
                                                const float* __restrict__ b2) {
    int i = blockIdx.y;
    if (i > g_nbp) return;          // unused intervals: skip (content data-dep, grid fixed)
    int c = blockIdx.x * 256 + threadIdx.x;
    float rm = g_rmid[i];
    float accA = 0.0f, accB = 0.0f;
    #pragma unroll 4
    for (int k = 0; k < H; ++k) {
        float a = W1[k], b = b1[k];
        float w2 = W2[k * NC + c];
        bool act = (a * rm + b) > 0.0f;       // matches relu gate for any radius in interval i
        accA += act ? a * w2 : 0.0f;
        accB += act ? b * w2 : 0.0f;
    }
    g_A[i * NC + c] = accA;
    g_B[i * NC + c] = accB + b2[c];
}

// ---------------- Main: 1 thread per output float4, fully coalesced stores ----------------
// Block = one edge (256 threads x 16 iters = 4096 float4 = 128x128 floats).
__global__ __launch_bounds__(256) void main_kernel(const float* __restrict__ lin_w0,
                                                   const float* __restrict__ lin_w1,
                                                   float* __restrict__ out, int N) {
    int n = blockIdx.x;
    if (n >= N) return;
    int idx = g_eidx[n];
    float4* o4 = reinterpret_cast<float4*>(out + (size_t)n * (DD * DD));

    const float n0   = 0.125f;                  // 1/sqrt(2*MUL)
    const float n1   = 0.10206207261596575f;    // 1/sqrt(3*MUL)
    const float ns   = 0.07216878364870323f;    // n0/sqrt(3) == n1/sqrt(2)

    if (idx >= 0) {
        float4 ey = g_ey[n];
        float Y0 = ey.x, Y1 = ey.y, Y2 = ey.z;
        float rad = ey.w;
        const float* __restrict__ A = g_A + (size_t)idx * NC;
        const float* __restrict__ B = g_B + (size_t)idx * NC;

        #pragma unroll
        for (int it = 0; it < 16; ++it) {
            int pos  = it * 256 + threadIdx.x;   // float4 index in the 128x128 tile
            int row  = pos >> 5;                 // 32 float4 per row
            int col0 = (pos & 31) << 2;          // first of 4 consecutive columns
            float v[4];
            if (row < MUL) {
                int w = row;
                if (col0 < MUL) {
                    // K00 = n0 * R0a[w,u]
                    #pragma unroll
                    for (int q = 0; q < 4; ++q) {
                        int c = w * MUL + col0 + q;                  // p=0
                        v[q] = n0 * (rad * A[c] + B[c]);
                    }
                } else {
                    // K01 = (n0/sqrt3) * R1b[w,u] * Y[i]
                    #pragma unroll
                    for (int q = 0; q < 4; ++q) {
                        int cc = col0 + q - MUL;
                        int u  = (cc * 171) >> 9;                    // cc / 3
                        int i  = cc - 3 * u;
                        int c  = 3 * (MUL * MUL) + w * MUL + u;      // p=3
                        v[q] = ns * (rad * A[c] + B[c]) * sel3(i, Y0, Y1, Y2);
                    }
                }
            } else {
                int rr = row - MUL;
                int w  = (rr * 171) >> 9;                            // rr / 3
                int j  = rr - 3 * w;
                float Yj = sel3(j, Y0, Y1, Y2);
                int jp = (j == 2) ? 0 : (j + 1);                     // (j+1)%3
                if (col0 < MUL) {
                    // K10 = n1 * R1a[w,u] * Y[j]
                    #pragma unroll
                    for (int q = 0; q < 4; ++q) {
                        int c = 2 * (MUL * MUL) + w * MUL + col0 + q; // p=2
                        v[q] = n1 * (rad * A[c] + B[c]) * Yj;
                    }
                } else {
                    // K11 = n1*R0b[w,u]*delta(j,i) + (n1/sqrt2)*R1c[w,u]*E[j][i]
                    // E = [[0,Y2,-Y1],[-Y2,0,Y0],[Y1,-Y0,0]]
                    #pragma unroll
                    for (int q = 0; q < 4; ++q) {
                        int cc = col0 + q - MUL;
                        int u  = (cc * 171) >> 9;
                        int i  = cc - 3 * u;
                        int c1 = 1 * (MUL * MUL) + w * MUL + u;      // p=1 (R0b)
                        int c4 = 4 * (MUL * MUL) + w * MUL + u;      // p=4 (R1c)
                        float rb = rad * A[c1] + B[c1];
                        float rc = rad * A[c4] + B[c4];
                        float Yk = sel3(3 - i - j, Y0, Y1, Y2);      // valid when i != j
                        float sgn = (jp == i) ? 1.0f : -1.0f;
                        v[q] = (i == j) ? (n1 * rb) : (sgn * ns * rc * Yk);
                    }
                }
            }
            o4[pos] = make_float4(v[0], v[1], v[2], v[3]);
        }
    } else {
        // fallback KernelLinear: block-diag, scaled 1/sqrt(MUL)
        const float s = 0.17677669529663687f;
        #pragma unroll
        for (int it = 0; it < 16; ++it) {
            int pos  = it * 256 + threadIdx.x;
            int row  = pos >> 5;
            int col0 = (pos & 31) << 2;
            float v[4] = {0.0f, 0.0f, 0.0f, 0.0f};
            if (row < MUL) {
                if (col0 < MUL) {
                    #pragma unroll
                    for (int q = 0; q < 4; ++q)
                        v[q] = s * lin_w0[row * MUL + col0 + q];
                }
            } else if (col0 >= MUL) {
                int rr = row - MUL;
                int w  = (rr * 171) >> 9;
                int j  = rr - 3 * w;
                float lw = s * lin_w1[w * MUL + 0];  // placeholder, per-q u below
                (void)lw;
                #pragma unroll
                for (int q = 0; q < 4; ++q) {
                    int cc = col0 + q - MUL;
                    int u  = (cc * 171) >> 9;
                    int i  = cc - 3 * u;
                    v[q] = (i == j) ? s * lin_w1[w * MUL + u] : 0.0f;
                }
            }
            o4[pos] = make_float4(v[0], v[1], v[2], v[3]);
        }
    }
}

extern "C" void kernel_launch(void* const* d_in, const int* in_sizes, int n_in,
                              void* d_out, int out_size, void* d_ws, size_t ws_size,
                              hipStream_t stream) {
    const float* r   = (const float*)d_in[0];
    const float* W1  = (const float*)d_in[1];
    const float* b1  = (const float*)d_in[2];
    const float* W2  = (const float*)d_in[3];
    const float* b2  = (const float*)d_in[4];
    const float* lw0 = (const float*)d_in[5];
    const float* lw1 = (const float*)d_in[6];
    float* out = (float*)d_out;
    int N = in_sizes[0] / 3;

    prep_bp<<<dim3(1), dim3(H), 0, stream>>>(W1, b1);
    prep_edges<<<dim3((N + 255) / 256), dim3(256), 0, stream>>>(r, N);
    prep_tab<<<dim3(NC / 256, NIV), dim3(256), 0, stream>>>(W1, b1, W2, b2);
    main_kernel<<<dim3(N), dim3(256), 0, stream>>>(lw0, lw1, out, N);
}

// Round 3
// 73.196 us; speedup vs baseline: 2.0890x; 2.0890x over previous
//
#include <hip/hip_runtime.h>
#include <math.h>

#define H 128
#define MUL 32
#define NC (5 * MUL * MUL)   // 5120 columns of R
#define DD (4 * MUL)         // 128 output dim
#define NIV (H + 1)          // max intervals = 129

// Static device scratch. Recomputed every launch (deterministic).
__device__ float g_bp[H];            // sorted breakpoints (invalid = +huge)
__device__ int   g_nbp;              // number of valid breakpoints
__device__ float g_rmid[NIV];        // representative radius per interval
__device__ float g_A[NIV * NC];      // norm-scaled: R_scaled = rad*A + B per interval
__device__ float g_B[NIV * NC];

__device__ __forceinline__ float sel3(int i, float a, float b, float c) {
    return (i == 0) ? a : ((i == 1) ? b : c);
}

// ---------------- P1: breakpoints, sort, interval midpoints ----------------
__global__ void prep_bp(const float* __restrict__ W1, const float* __restrict__ b1) {
    __shared__ float bp[H];
    __shared__ float sorted[H];
    int k = threadIdx.x;             // blockDim = 128
    float a = W1[k], b = b1[k];
    float v = 3.0e38f;               // invalid sentinel
    if (a != 0.0f) {
        float t = -b / a;
        if (t > 0.0f) v = t;
    }
    bp[k] = v;
    __syncthreads();
    int rank = 0, nv = 0;
    #pragma unroll 8
    for (int j = 0; j < H; ++j) {
        float bj = bp[j];
        rank += (bj < v) || (bj == v && j < k);
        nv   += (bj < 3.0e38f);
    }
    sorted[rank] = v;
    __syncthreads();
    g_bp[k] = sorted[k];
    if (k == 0) g_nbp = nv;
    int nbp = nv;
    for (int i = k; i <= H; i += H) {
        float rm;
        if (nbp == 0)       rm = 1.0f;
        else if (i == 0)    rm = 0.5f * sorted[0];
        else if (i >= nbp)  rm = sorted[nbp - 1] + 1.0f;
        else                rm = 0.5f * (sorted[i - 1] + sorted[i]);
        g_rmid[i] = rm;
    }
}

// ---------------- P2: per-interval rank-1 tables A,B (norm consts folded) ----------------
__global__ __launch_bounds__(256) void prep_tab(const float* __restrict__ W1,
                                                const float* __restrict__ b1,
                                                const float* __restrict__ W2,
                                                const float* __restrict__ b2) {
    int i = blockIdx.y;
    if (i > g_nbp) return;
    int c = blockIdx.x * 256 + threadIdx.x;
    float rm = g_rmid[i];
    float accA = 0.0f, accB = 0.0f;
    #pragma unroll 4
    for (int k = 0; k < H; ++k) {
        float a = W1[k], b = b1[k];
        float w2 = W2[k * NC + c];
        bool act = (a * rm + b) > 0.0f;
        accA += act ? a * w2 : 0.0f;
        accB += act ? b * w2 : 0.0f;
    }
    // fold per-path norm: p0 -> n0, p1/p2 -> n1, p3/p4 -> ns
    int p = c >> 10;
    const float n0 = 0.125f;                  // 1/sqrt(2*MUL)
    const float n1 = 0.10206207261596575f;    // 1/sqrt(3*MUL)
    const float ns = 0.07216878364870323f;    // n0/sqrt(3) == n1/sqrt(2)
    float s = (p == 0) ? n0 : ((p <= 2) ? n1 : ns);
    g_A[i * NC + c] = s * accA;
    g_B[i * NC + c] = s * (accB + b2[c]);
}

// ---------------- Main: one block per edge; LDS-staged R; quadrant-uniform passes ----------------
__global__ __launch_bounds__(256) void main_kernel(const float* __restrict__ r,
                                                   const float* __restrict__ lin_w0,
                                                   const float* __restrict__ lin_w1,
                                                   float* __restrict__ out, int N) {
    __shared__ float Rs[5 * 1024];   // swizzled R table: 20 KB
    float4* Rs4 = reinterpret_cast<float4*>(Rs);
    int n = blockIdx.x;
    if (n >= N) return;
    int tid = threadIdx.x;

    // per-edge scalars (computed redundantly; r loads are broadcast, L2-hot)
    float x = r[3 * n], y = r[3 * n + 1], z = r[3 * n + 2];
    float rad = sqrtf(x * x + y * y + z * z);
    bool mask = rad > 0.1f;
    float inv = mask ? (1.7320508075688772f / rad) : 0.0f;   // sqrt(3)/rad
    float Y0 = x * inv, Y1 = y * inv, Y2 = z * inv;

    float4* o4 = reinterpret_cast<float4*>(out + (size_t)n * (DD * DD));

    if (mask) {
        int nbp = g_nbp;
        int idx = 0;
        for (int jj = 0; jj < nbp; ++jj) idx += (g_bp[jj] < rad) ? 1 : 0;
        const float4* A4 = reinterpret_cast<const float4*>(g_A + (size_t)idx * NC);
        const float4* B4 = reinterpret_cast<const float4*>(g_B + (size_t)idx * NC);

        // stage R = rad*A + B into LDS, XOR-swizzled float4 columns
        int sw_w = tid >> 3, sw_u4 = tid & 7;
        int physBase = sw_w * 8 + (sw_u4 ^ (sw_w & 7));
        #pragma unroll
        for (int k = 0; k < 5; ++k) {
            int c4 = k * 256 + tid;
            float4 a = A4[c4], b = B4[c4];
            Rs4[k * 256 + physBase] = make_float4(fmaf(rad, a.x, b.x), fmaf(rad, a.y, b.y),
                                                  fmaf(rad, a.z, b.z), fmaf(rad, a.w, b.w));
        }
        __syncthreads();

        // ---- K00: 32 rows x 8 f4 (1 pass): val = R0[w][u]
        {
            int row = tid >> 3, c4 = tid & 7;
            float4 v = Rs4[row * 8 + (c4 ^ (row & 7))];
            o4[row * 32 + c4] = v;
        }
        // ---- K01: 32 rows x 24 f4 (3 passes): val = R3[w][u] * Y[i]
        #pragma unroll
        for (int ps = 0; ps < 3; ++ps) {
            int t = ps * 256 + tid;
            int row = (t * 2731) >> 16;          // t / 24
            int cc4 = t - row * 24;
            float vv[4];
            #pragma unroll
            for (int q = 0; q < 4; ++q) {
                int cc = cc4 * 4 + q;
                int u = (cc * 171) >> 9;         // cc / 3
                int i = cc - 3 * u;
                float rv = Rs[3 * 1024 + row * 32 + ((((u >> 2) ^ (row & 7)) << 2) | (u & 3))];
                vv[q] = rv * sel3(i, Y0, Y1, Y2);
            }
            o4[row * 32 + 8 + cc4] = make_float4(vv[0], vv[1], vv[2], vv[3]);
        }
        // ---- K10: 96 rows x 8 f4 (3 passes): val = R2[w][u] * Y[j]
        #pragma unroll
        for (int ps = 0; ps < 3; ++ps) {
            int t = ps * 256 + tid;
            int rr = t >> 3, c4 = t & 7;
            int w = (rr * 171) >> 9, j = rr - 3 * w;
            float Yj = sel3(j, Y0, Y1, Y2);
            float4 v = Rs4[2 * 256 + w * 8 + (c4 ^ (w & 7))];
            o4[(32 + rr) * 32 + c4] = make_float4(v.x * Yj, v.y * Yj, v.z * Yj, v.w * Yj);
        }
        // ---- K11: 96 rows x 24 f4 (9 passes): diag R1[w][u], off-diag sgn*R4[w][u]*Yk
        #pragma unroll
        for (int ps = 0; ps < 9; ++ps) {
            int t = ps * 256 + tid;
            int rr = (t * 2731) >> 16;           // t / 24
            int cc4 = t - rr * 24;
            int w = (rr * 171) >> 9, j = rr - 3 * w;
            int jp = (j == 2) ? 0 : (j + 1);
            float vv[4];
            #pragma unroll
            for (int q = 0; q < 4; ++q) {
                int cc = cc4 * 4 + q;
                int u = (cc * 171) >> 9;
                int i = cc - 3 * u;
                int sw = (((u >> 2) ^ (w & 7)) << 2) | (u & 3);
                float r1 = Rs[1 * 1024 + w * 32 + sw];
                float r4 = Rs[4 * 1024 + w * 32 + sw];
                float Yk = sel3(3 - i - j, Y0, Y1, Y2);   // valid when i != j
                float sgn = (i == jp) ? 1.0f : -1.0f;
                vv[q] = (i == j) ? r1 : sgn * r4 * Yk;
            }
            o4[(32 + rr) * 32 + 8 + cc4] = make_float4(vv[0], vv[1], vv[2], vv[3]);
        }
    } else {
        // fallback KernelLinear: block-diag, scaled 1/sqrt(MUL)
        const float s = 0.17677669529663687f;
        float4 z4 = make_float4(0.0f, 0.0f, 0.0f, 0.0f);
        {
            int row = tid >> 3, c4 = tid & 7;
            const float4* l0 = reinterpret_cast<const float4*>(lin_w0);
            float4 v = l0[row * 8 + c4];
            o4[row * 32 + c4] = make_float4(s * v.x, s * v.y, s * v.z, s * v.w);
        }
        #pragma unroll
        for (int ps = 0; ps < 3; ++ps) {
            int t = ps * 256 + tid;
            int row = (t * 2731) >> 16;
            int cc4 = t - row * 24;
            o4[row * 32 + 8 + cc4] = z4;
        }
        #pragma unroll
        for (int ps = 0; ps < 3; ++ps) {
            int t = ps * 256 + tid;
            int rr = t >> 3, c4 = t & 7;
            o4[(32 + rr) * 32 + c4] = z4;
        }
        #pragma unroll
        for (int ps = 0; ps < 9; ++ps) {
            int t = ps * 256 + tid;
            int rr = (t * 2731) >> 16;
            int cc4 = t - rr * 24;
            int w = (rr * 171) >> 9, j = rr - 3 * w;
            float vv[4];
            #pragma unroll
            for (int q = 0; q < 4; ++q) {
                int cc = cc4 * 4 + q;
                int u = (cc * 171) >> 9;
                int i = cc - 3 * u;
                vv[q] = (i == j) ? s * lin_w1[w * MUL + u] : 0.0f;
            }
            o4[(32 + rr) * 32 + 8 + cc4] = make_float4(vv[0], vv[1], vv[2], vv[3]);
        }
    }
}

extern "C" void kernel_launch(void* const* d_in, const int* in_sizes, int n_in,
                              void* d_out, int out_size, void* d_ws, size_t ws_size,
                              hipStream_t stream) {
    const float* r   = (const float*)d_in[0];
    const float* W1  = (const float*)d_in[1];
    const float* b1  = (const float*)d_in[2];
    const float* W2  = (const float*)d_in[3];
    const float* b2  = (const float*)d_in[4];
    const float* lw0 = (const float*)d_in[5];
    const float* lw1 = (const float*)d_in[6];
    float* out = (float*)d_out;
    int N = in_sizes[0] / 3;

    prep_bp<<<dim3(1), dim3(H), 0, stream>>>(W1, b1);
    prep_tab<<<dim3(NC / 256, NIV), dim3(256), 0, stream>>>(W1, b1, W2, b2);
    main_kernel<<<dim3(N), dim3(256), 0, stream>>>(r, lw0, lw1, out, N);
}